// Round 21
// baseline (84.131 us; speedup 1.0000x reference)
//
#include <hip/hip_runtime.h>
#include <hip/hip_fp16.h>
#include <math.h>

#define B_  16
#define H_  8
#define L_  512
#define DM_ 512
#define DK_ 64
#define LOG2E_ 1.44269504088896340736f
#define NLOG2E_H_ 0.72134752044f   // 0.5 * log2(e)

typedef _Float16 f16;
typedef __attribute__((ext_vector_type(2)))  __fp16   fp16v2;
typedef __attribute__((ext_vector_type(8)))  _Float16 f16x8;
typedef __attribute__((ext_vector_type(16))) float f32x16;

__device__ __forceinline__ unsigned pkrtz(float a, float b) {
    union { fp16v2 v; unsigned u; } cv;
    cv.v = __builtin_amdgcn_cvt_pkrtz(a, b);
    return cv.u;
}
// v_permlane32_swap_b32: x[lanes 32..63] <-> y[lanes 0..31]
__device__ __forceinline__ void plswap(unsigned &x, unsigned &y) {
    asm("v_permlane32_swap_b32 %0, %1" : "+v"(x), "+v"(y));
}

// ---------------------------------------------------------------------------
// W pre-pack (unchanged): Wpk[nb][ks][hf][lane][8].
// ---------------------------------------------------------------------------
__global__ __launch_bounds__(256) void convw_pack(
    const float* __restrict__ Wq, const float* __restrict__ Wk,
    const float* __restrict__ Wv, const float* __restrict__ Wo,
    f16* __restrict__ Wpk)
{
    const float* src[4] = {Wq, Wk, Wv, Wo};
    const int t = blockIdx.x * 256 + threadIdx.x;
    const int m    = t >> 15;
    const int r    = t & 32767;
    const int lane = r & 31;
    const int hf   = (r >> 5) & 1;
    const int ks   = (r >> 6) & 31;
    const int nb   = r >> 11;
    const float* p = src[m] + (size_t)(nb * 32 + lane) * 512 + ks * 16 + hf * 8;
    float4 x0 = *(const float4*)(p);
    float4 x1 = *(const float4*)(p + 4);
    uint4 v;
    v.x = pkrtz(x0.x, x0.y); v.y = pkrtz(x0.z, x0.w);
    v.z = pkrtz(x1.x, x1.y); v.w = pkrtz(x1.z, x1.w);
    *(uint4*)&Wpk[(size_t)m * 262144 + (size_t)r * 8] = v;
}

// ---------------------------------------------------------------------------
// Stream GEMM core (unchanged).  OUTMODE: 0 row-major, 1 Vpk, 2 Kpk.
// ---------------------------------------------------------------------------
template<int XF16, int OUTF32, int OUTMODE, int NWAVES, int NT>
__device__ __forceinline__ void gemm_stream_core(
    const void* __restrict__ Xv, const f16* __restrict__ Wpk_m,
    const float* __restrict__ bias, void* __restrict__ Yv,
    int row0, int col0, f16* Xl)
{
    const int tid   = threadIdx.x;
    const int w     = tid >> 6;
    const int lane  = tid & 63;
    const int lq    = lane & 31;
    const int half_ = lane >> 5;
    const int colw  = col0 + w * (NT * 32);

    {
        constexpr int TPR = NWAVES * 64 / 32;
        constexpr int FPT = 512 / TPR;
        const int r = tid / TPR, s = tid % TPR;
        const unsigned swz = (r & 7) << 4;
        if (XF16) {
            const f16* X = (const f16*)Xv + (size_t)(row0 + r) * 512 + s * FPT;
            #pragma unroll
            for (int j = 0; j < FPT / 8; ++j) {
                uint4 v = *(const uint4*)(X + j * 8);
                *(uint4*)((char*)Xl + ((r * 1024 + s * FPT * 2 + j * 16) ^ swz)) = v;
            }
        } else {
            const float* X = (const float*)Xv + (size_t)(row0 + r) * 512 + s * FPT;
            #pragma unroll
            for (int j = 0; j < FPT / 8; ++j) {
                float4 x0 = *(const float4*)(X + j * 8);
                float4 x1 = *(const float4*)(X + j * 8 + 4);
                uint4 v;
                v.x = pkrtz(x0.x, x0.y); v.y = pkrtz(x0.z, x0.w);
                v.z = pkrtz(x1.x, x1.y); v.w = pkrtz(x1.z, x1.w);
                *(uint4*)((char*)Xl + ((r * 1024 + s * FPT * 2 + j * 16) ^ swz)) = v;
            }
        }
    }
    __syncthreads();

    f32x16 acc[NT];
    #pragma unroll
    for (int nt = 0; nt < NT; ++nt)
        #pragma unroll
        for (int i = 0; i < 16; ++i) acc[nt][i] = 0.f;

    const f16* wp[NT];
    #pragma unroll
    for (int nt = 0; nt < NT; ++nt)
        wp[nt] = Wpk_m + ((size_t)((colw / 32 + nt) * 64 + half_)) * 256 + lq * 8;

    const unsigned aswz = (lq & 7) << 4;

    #pragma unroll 4
    for (int ks = 0; ks < 32; ++ks) {
        f16x8 a = *(const f16x8*)((char*)Xl + ((lq * 1024 + ks * 32 + half_ * 16) ^ aswz));
        f16x8 bfr[NT];
        #pragma unroll
        for (int nt = 0; nt < NT; ++nt)
            bfr[nt] = *(const f16x8*)(wp[nt] + (size_t)ks * 512);
        #pragma unroll
        for (int nt = 0; nt < NT; ++nt) {
            if (OUTMODE == 2)
                acc[nt] = __builtin_amdgcn_mfma_f32_32x32x16_f16(bfr[nt], a, acc[nt], 0, 0, 0);
            else
                acc[nt] = __builtin_amdgcn_mfma_f32_32x32x16_f16(a, bfr[nt], acc[nt], 0, 0, 0);
        }
    }

    if (OUTMODE == 2) {
        const int b  = row0 >> 9;
        const int cb = (row0 >> 5) & 15;
        f16* Kp = (f16*)Yv + (size_t)(b * H_ + w) * 32768;
        #pragma unroll
        for (int nt = 0; nt < NT; ++nt)
            #pragma unroll
            for (int g = 0; g < 4; ++g) {
                const int n0 = w * 64 + nt * 32 + 8 * g + 4 * half_;
                const float4 b4 = *(const float4*)&bias[n0];
                const int ks2 = nt * 2 + (g >> 1);
                uint2 v;
                v.x = pkrtz(acc[nt][4 * g + 0] + b4.x, acc[nt][4 * g + 1] + b4.y);
                v.y = pkrtz(acc[nt][4 * g + 2] + b4.z, acc[nt][4 * g + 3] + b4.w);
                *(uint2*)&Kp[(cb * 4 + ks2) * 512 + (g & 1) * 256 + lq * 8 + half_ * 4] = v;
            }
    } else if (OUTMODE == 1) {
        const int b  = row0 >> 9;
        const int cB = row0 & 511;
        const int tt = cB >> 6;
        const int kbase = (cB >> 4) & 3;
        f16* Vp = (f16*)Yv + (size_t)(b * H_ + w) * 32768;
        #pragma unroll
        for (int nt = 0; nt < NT; ++nt) {
            const float bv = bias[w * 64 + nt * 32 + lq];
            #pragma unroll
            for (int g = 0; g < 4; ++g) {
                const int ks2 = kbase + (g >> 1);
                uint2 v;
                v.x = pkrtz(acc[nt][4 * g + 0] + bv, acc[nt][4 * g + 1] + bv);
                v.y = pkrtz(acc[nt][4 * g + 2] + bv, acc[nt][4 * g + 3] + bv);
                *(uint2*)&Vp[((tt * 4 + ks2) * 2 + nt) * 512 + (g & 1) * 256 + lq * 8 + half_ * 4] = v;
            }
        }
    } else {
        #pragma unroll
        for (int nt = 0; nt < NT; ++nt) {
            const float bv = bias[colw + nt * 32 + lq];
            #pragma unroll
            for (int r = 0; r < 16; ++r) {
                const int row = row0 + (r & 3) + 8 * (r >> 2) + 4 * half_;
                const float v = acc[nt][r] + bv;
                const size_t off = (size_t)row * 512 + colw + nt * 32 + lq;
                if (OUTF32) ((float*)Yv)[off] = v;
                else        ((f16*)Yv)[off]   = (f16)v;
            }
        }
    }
}

__global__ __launch_bounds__(512) void gemm_qkv(
    const float* __restrict__ query, const float* __restrict__ key,
    const float* __restrict__ value, const f16* __restrict__ Wpk,
    const float* __restrict__ bq, const float* __restrict__ bk,
    const float* __restrict__ bv,
    void* __restrict__ Qb, void* __restrict__ Kpk, void* __restrict__ Vpk)
{
    __shared__ f16 Xl[32 * 512];
    const int wg  = blockIdx.x;
    const int xcd = wg & 7;
    const int i   = wg >> 3;
    const int pg  = xcd * 96 + i;
    const int z   = pg >> 8;
    const int y   = pg & 255;
    const int row0 = y * 32;

    if (z == 0)
        gemm_stream_core<0, 0, 0, 8, 2>(query, Wpk,          bq, Qb,  row0, 0, Xl);
    else if (z == 1)
        gemm_stream_core<0, 0, 2, 8, 2>(key,   Wpk + 262144, bk, Kpk, row0, 0, Xl);
    else
        gemm_stream_core<0, 0, 1, 8, 2>(value, Wpk + 524288, bv, Vpk, row0, 0, Xl);
}

__global__ __launch_bounds__(256) void gemm_o(
    const void* __restrict__ X, const f16* __restrict__ Wpk,
    const float* __restrict__ bo, void* __restrict__ Y)
{
    __shared__ f16 Xl[32 * 512];
    const int wg  = blockIdx.x;
    const int xcd = wg & 7;
    const int i   = wg >> 3;
    const int pg  = xcd * 64 + i;
    const int cb  = pg & 1;
    const int y   = pg >> 1;
    gemm_stream_core<1, 1, 0, 4, 2>(X, Wpk + 786432, bo, Y, y * 32, cb * 256, Xl);
}

// ---------------------------------------------------------------------------
// Flash attention, split-K x2 on the 4-wave structure:
// 1024 blocks x 256 thr; waves (0,1) share q-rows [q0,q0+32) and split KV
// tiles 0-3 / 4-7; waves (2,3) likewise for [q0+32,q0+64).  Pairs merge via
// LDS with the R7-proven exp(m_i - m) correction.  4096 waves = ~16/CU.
// ---------------------------------------------------------------------------
__global__ __launch_bounds__(256) void attn_kernel(
    const f16* __restrict__ Q, const f16* __restrict__ Kpk,
    const f16* __restrict__ Vpk, const float* __restrict__ Wg,
    const float* __restrict__ bg, const float* __restrict__ lam1,
    f16* __restrict__ ATT)
{
    __shared__ float Lm[2][64], Lss[2][64], Lsa[2][64];
    __shared__ float Lacc[2][4][16][64];

    const int tid  = threadIdx.x;
    const int w    = tid >> 6;
    const int pr   = w >> 1;          // q-pair id (0,1)
    const int ws   = w & 1;           // split-K id (0,1)
    const int lane = tid & 63;
    const int lq   = lane & 31;
    const int half = lane >> 5;
    const int bh   = blockIdx.x;      // same bh -> same XCD
    const int b    = bh >> 3;
    const int h    = bh & 7;
    const int q0w  = blockIdx.y * 64 + pr * 32;
    const int q    = q0w + lq;

    const float sg  = 1.f / (1.f + __expf(-lam1[0]));
    const float osg = 1.f - sg;

    // Q fragments (B-operand)
    f16x8 qh[4];
    {
        const f16* qrow = Q + ((size_t)(b * L_ + q) * DM_ + h * DK_);
        #pragma unroll
        for (int db = 0; db < 4; ++db)
            qh[db] = *(const f16x8*)&qrow[db * 16 + 8 * half];
    }

    // fused gamma: g = q_row . Wg^T + bg ; qp = (|g|+1)^-2
    float A0, A1, qpw;
    {
        float g0 = 0.f, g1 = 0.f;
        #pragma unroll
        for (int db = 0; db < 4; ++db)
            #pragma unroll
            for (int j = 0; j < 8; ++j) {
                const int d = db * 16 + 8 * half + j;
                const float qv = (float)qh[db][j];
                g0 = fmaf(qv, Wg[d], g0);
                g1 = fmaf(qv, Wg[64 + d], g1);
            }
        g0 += __shfl_xor(g0, 32);
        g1 += __shfl_xor(g1, 32);
        g0 += bg[0];
        g1 += bg[1];
        const float t0 = fabsf(g0) + 1.f, t1 = fabsf(g1) + 1.f;
        const float p0 = 1.f / (t0 * t0), p1 = 1.f / (t1 * t1);
        A0 = -NLOG2E_H_ * p0;       // c >= q (triu)
        A1 = -NLOG2E_H_ * p1;       // c <  q (tril)
        float mn = NLOG2E_H_ * fminf(p0, p1);
        #pragma unroll
        for (int off = 1; off < 64; off <<= 1) mn = fminf(mn, __shfl_xor(mn, off));
        qpw = mn;
    }

    f32x16 aS0, aS1, aA0, aA1;
    #pragma unroll
    for (int i = 0; i < 16; ++i) { aS0[i] = 0.f; aS1[i] = 0.f; aA0[i] = 0.f; aA1[i] = 0.f; }
    float m2 = -3.0e38f, sumS = 0.f, sumA = 0.f;

    const f16* Kp = Kpk + (size_t)(b * H_ + h) * 32768;
    const f16* Vp = Vpk + (size_t)(b * H_ + h) * 32768;
    const int  fo = half * 256 + lq * 8;

    for (int tt = 0; tt < 4; ++tt) {
        const int t  = ws * 4 + tt;
        const int c0 = t * 64;

        // K fragment loads (1KB contiguous per instr)
        f16x8 ka[4], kb2[4];
        #pragma unroll
        for (int db = 0; db < 4; ++db) {
            ka[db]  = *(const f16x8*)&Kp[(t * 2 * 4 + db) * 512 + fo];
            kb2[db] = *(const f16x8*)&Kp[((t * 2 + 1) * 4 + db) * 512 + fo];
        }

        // S^T = K . Q^T
        f32x16 s2a, s2b;
        #pragma unroll
        for (int i = 0; i < 16; ++i) { s2a[i] = 0.f; s2b[i] = 0.f; }
        __builtin_amdgcn_s_setprio(1);
        #pragma unroll
        for (int db = 0; db < 4; ++db) {
            s2a = __builtin_amdgcn_mfma_f32_32x32x16_f16(ka[db],  qh[db], s2a, 0, 0, 0);
            s2b = __builtin_amdgcn_mfma_f32_32x32x16_f16(kb2[db], qh[db], s2b, 0, 0, 0);
        }
        __builtin_amdgcn_s_setprio(0);

        // V fragment loads: latency hides under softmax VALU; K regs dead.
        f16x8 vfa[4], vfb[4];
        #pragma unroll
        for (int ks = 0; ks < 4; ++ks) {
            vfa[ks] = *(const f16x8*)&Vp[((t * 4 + ks) * 2 + 0) * 512 + fo];
            vfb[ks] = *(const f16x8*)&Vp[((t * 4 + ks) * 2 + 1) * 512 + fo];
        }

        // online max, exact skip
        float tm = s2a[0];
        #pragma unroll
        for (int i = 1; i < 16; ++i) tm = fmaxf(tm, s2a[i]);
        #pragma unroll
        for (int i = 0; i < 16; ++i) tm = fmaxf(tm, s2b[i]);
        tm = fmaxf(tm, __shfl_xor(tm, 32));
        if (__any(tm > m2)) {
            const float nm = fmaxf(m2, tm);
            const float sc = exp2f((m2 - nm) * LOG2E_);
            m2 = nm;
            sumS *= sc;
            #pragma unroll
            for (int r = 0; r < 16; ++r) {
                const float s_ = __shfl(sc, (r & 3) + 8 * (r >> 2) + 4 * half);
                aS0[r] *= s_;
                aS1[r] *= s_;
            }
        }

        // P: exp, pack, permlane-swap into A-fragments, PV MFMAs
        const float nmL = m2 * LOG2E_;
        #pragma unroll
        for (int sub = 0; sub < 2; ++sub) {
            const f32x16& s2 = sub ? s2b : s2a;
            #pragma unroll
            for (int ksl = 0; ksl < 2; ++ksl) {
                const int rb = ksl * 8;
                float p[8];
                #pragma unroll
                for (int rr = 0; rr < 8; ++rr) {
                    p[rr] = exp2f(fmaf(s2[rb + rr], LOG2E_, -nmL));
                    sumS += p[rr];
                }
                union { unsigned u[4]; f16x8 v; } f;
                f.u[0] = pkrtz(p[0], p[1]);
                f.u[1] = pkrtz(p[2], p[3]);
                f.u[2] = pkrtz(p[4], p[5]);
                f.u[3] = pkrtz(p[6], p[7]);
                plswap(f.u[0], f.u[2]);
                plswap(f.u[1], f.u[3]);
                const int ks = sub * 2 + ksl;
                __builtin_amdgcn_s_setprio(1);
                aS0 = __builtin_amdgcn_mfma_f32_32x32x16_f16(f.v, vfa[ks], aS0, 0, 0, 0);
                aS1 = __builtin_amdgcn_mfma_f32_32x32x16_f16(f.v, vfb[ks], aS1, 0, 0, 0);
                __builtin_amdgcn_s_setprio(0);
            }
        }

        // adjacency branch (band-skip far tiles; diagonal tile never skipped)
        int gl_ = q0w - (c0 + 63);
        int gh_ = c0 - (q0w + 31);
        int dmin = gl_ > gh_ ? gl_ : gh_;
        if (dmin < 0) dmin = 0;
        if (qpw * (float)(dmin * dmin) < 40.0f) {
            #pragma unroll
            for (int sub = 0; sub < 2; ++sub) {
                #pragma unroll
                for (int ksl = 0; ksl < 2; ++ksl) {
                    float a[8];
                    #pragma unroll
                    for (int rr = 0; rr < 8; ++rr) {
                        const int kk = (rr & 3) + 8 * (rr >> 2) + 16 * ksl + 4 * half;
                        const int diff = q - (c0 + sub * 32 + kk);
                        const float fd = (float)diff;
                        const float coef = diff > 0 ? A1 : A0;
                        a[rr] = exp2f(coef * fd * fd);
                        sumA += a[rr];
                    }
                    union { unsigned u[4]; f16x8 v; } f;
                    f.u[0] = pkrtz(a[0], a[1]);
                    f.u[1] = pkrtz(a[2], a[3]);
                    f.u[2] = pkrtz(a[4], a[5]);
                    f.u[3] = pkrtz(a[6], a[7]);
                    plswap(f.u[0], f.u[2]);
                    plswap(f.u[1], f.u[3]);
                    const int ks = sub * 2 + ksl;
                    __builtin_amdgcn_s_setprio(1);
                    aA0 = __builtin_amdgcn_mfma_f32_32x32x16_f16(f.v, vfa[ks], aA0, 0, 0, 0);
                    aA1 = __builtin_amdgcn_mfma_f32_32x32x16_f16(f.v, vfb[ks], aA1, 0, 0, 0);
                    __builtin_amdgcn_s_setprio(0);
                }
            }
        }
    }

    // split-K merge: ws==1 dumps partials; ws==0 combines + writes (R7 form)
    if (ws == 1) {
        Lm[pr][lane]  = m2;
        Lss[pr][lane] = sumS;
        Lsa[pr][lane] = sumA;
        #pragma unroll
        for (int r = 0; r < 16; ++r) {
            Lacc[pr][0][r][lane] = aS0[r];
            Lacc[pr][1][r][lane] = aS1[r];
            Lacc[pr][2][r][lane] = aA0[r];
            Lacc[pr][3][r][lane] = aA1[r];
        }
    }
    __syncthreads();
    if (ws == 0) {
        const float m2p = Lm[pr][lane];
        const float nm  = fmaxf(m2, m2p);
        const float e0  = exp2f((m2  - nm) * LOG2E_);
        const float e1  = exp2f((m2p - nm) * LOG2E_);
        const float ssm = sumS * e0 + Lss[pr][lane] * e1;
        const float sam = sumA + Lsa[pr][lane];
        const float St  = ssm + __shfl_xor(ssm, 32);
        const float At  = sam + __shfl_xor(sam, 32);
        const float den = sg * St + osg * At + 1e-9f;
        #pragma unroll
        for (int r = 0; r < 16; ++r) {
            const int row = (r & 3) + 8 * (r >> 2) + 4 * half;
            const float dn  = __shfl(den, row);
            const float e0r = __shfl(e0, row);
            const float e1r = __shfl(e1, row);
            const float o0 = (sg * (aS0[r] * e0r + Lacc[pr][0][r][lane] * e1r)
                            + osg * (aA0[r] + Lacc[pr][2][r][lane])) / dn;
            const float o1 = (sg * (aS1[r] * e0r + Lacc[pr][1][r][lane] * e1r)
                            + osg * (aA1[r] + Lacc[pr][3][r][lane])) / dn;
            const size_t base = (size_t)(b * L_ + q0w + row) * DM_ + h * DK_;
            ATT[base + lq]      = (f16)o0;
            ATT[base + 32 + lq] = (f16)o1;
        }
    }
}

// ---------------------------------------------------------------------------
extern "C" void kernel_launch(void* const* d_in, const int* in_sizes, int n_in,
                              void* d_out, int out_size, void* d_ws, size_t ws_size,
                              hipStream_t stream)
{
    (void)in_sizes; (void)n_in; (void)out_size; (void)ws_size;
    const float* query = (const float*)d_in[0];
    const float* key   = (const float*)d_in[1];
    const float* value = (const float*)d_in[2];
    const float* Wq = (const float*)d_in[3];  const float* bq = (const float*)d_in[4];
    const float* Wk = (const float*)d_in[5];  const float* bk = (const float*)d_in[6];
    const float* Wv = (const float*)d_in[7];  const float* bv = (const float*)d_in[8];
    const float* Wg = (const float*)d_in[9];  const float* bg = (const float*)d_in[10];
    const float* lam1 = (const float*)d_in[11];
    const float* Wo = (const float*)d_in[12]; const float* bo = (const float*)d_in[13];

    f16* ws16 = (f16*)d_ws;
    const size_t NR = (size_t)B_ * L_ * DM_;
    f16* Kpkb = ws16;
    f16* Vpkb = ws16 + NR;
    f16* Qb   = ws16 + 2 * NR;
    f16* Wpkb = ws16 + 3 * NR;
    f16* ATTb = Qb;   // safe alias: each pair reads exactly the Q cells ws==0 later writes

    convw_pack<<<512, 256, 0, stream>>>(Wq, Wk, Wv, Wo, Wpkb);

    gemm_qkv<<<768, 512, 0, stream>>>(query, key, value, Wpkb, bq, bk, bv,
                                      Qb, Kpkb, Vpkb);

    dim3 ga(H_ * B_, L_ / 64);    // (128, 8) x 256 thr = 2 q-pairs x 2 split-K waves
    attn_kernel<<<ga, 256, 0, stream>>>(Qb, Kpkb, Vpkb, Wg, bg, lam1, ATTb);

    gemm_o<<<512, 256, 0, stream>>>(Qb, Wpkb, bo, (float*)d_out);
}

// Round 22
// 75.122 us; speedup vs baseline: 1.1199x; 1.1199x over previous
//
#include <hip/hip_runtime.h>
#include <hip/hip_fp16.h>
#include <math.h>

#define B_  16
#define H_  8
#define L_  512
#define DM_ 512
#define DK_ 64
#define LOG2E_ 1.44269504088896340736f
#define NLOG2E_H_ 0.72134752044f   // 0.5 * log2(e)

typedef _Float16 f16;
typedef __attribute__((ext_vector_type(2)))  __fp16   fp16v2;
typedef __attribute__((ext_vector_type(8)))  _Float16 f16x8;
typedef __attribute__((ext_vector_type(16))) float f32x16;

__device__ __forceinline__ unsigned pkrtz(float a, float b) {
    union { fp16v2 v; unsigned u; } cv;
    cv.v = __builtin_amdgcn_cvt_pkrtz(a, b);
    return cv.u;
}
// v_permlane32_swap_b32: x[lanes 32..63] <-> y[lanes 0..31]
__device__ __forceinline__ void plswap(unsigned &x, unsigned &y) {
    asm("v_permlane32_swap_b32 %0, %1" : "+v"(x), "+v"(y));
}

// ---------------------------------------------------------------------------
// W pre-pack: Wpk[nb][ks][hf][lane][8].
// ---------------------------------------------------------------------------
__global__ __launch_bounds__(256) void convw_pack(
    const float* __restrict__ Wq, const float* __restrict__ Wk,
    const float* __restrict__ Wv, const float* __restrict__ Wo,
    f16* __restrict__ Wpk)
{
    const float* src[4] = {Wq, Wk, Wv, Wo};
    const int t = blockIdx.x * 256 + threadIdx.x;
    const int m    = t >> 15;
    const int r    = t & 32767;
    const int lane = r & 31;
    const int hf   = (r >> 5) & 1;
    const int ks   = (r >> 6) & 31;
    const int nb   = r >> 11;
    const float* p = src[m] + (size_t)(nb * 32 + lane) * 512 + ks * 16 + hf * 8;
    float4 x0 = *(const float4*)(p);
    float4 x1 = *(const float4*)(p + 4);
    uint4 v;
    v.x = pkrtz(x0.x, x0.y); v.y = pkrtz(x0.z, x0.w);
    v.z = pkrtz(x1.x, x1.y); v.w = pkrtz(x1.z, x1.w);
    *(uint4*)&Wpk[(size_t)m * 262144 + (size_t)r * 8] = v;
}

// ---------------------------------------------------------------------------
// Stream GEMM core.  OUTMODE: 0 row-major, 1 Vpk, 2 Kpk.
// ---------------------------------------------------------------------------
template<int XF16, int OUTF32, int OUTMODE, int NWAVES, int NT>
__device__ __forceinline__ void gemm_stream_core(
    const void* __restrict__ Xv, const f16* __restrict__ Wpk_m,
    const float* __restrict__ bias, void* __restrict__ Yv,
    int row0, int col0, f16* Xl)
{
    const int tid   = threadIdx.x;
    const int w     = tid >> 6;
    const int lane  = tid & 63;
    const int lq    = lane & 31;
    const int half_ = lane >> 5;
    const int colw  = col0 + w * (NT * 32);

    {
        constexpr int TPR = NWAVES * 64 / 32;
        constexpr int FPT = 512 / TPR;
        const int r = tid / TPR, s = tid % TPR;
        const unsigned swz = (r & 7) << 4;
        if (XF16) {
            const f16* X = (const f16*)Xv + (size_t)(row0 + r) * 512 + s * FPT;
            #pragma unroll
            for (int j = 0; j < FPT / 8; ++j) {
                uint4 v = *(const uint4*)(X + j * 8);
                *(uint4*)((char*)Xl + ((r * 1024 + s * FPT * 2 + j * 16) ^ swz)) = v;
            }
        } else {
            const float* X = (const float*)Xv + (size_t)(row0 + r) * 512 + s * FPT;
            #pragma unroll
            for (int j = 0; j < FPT / 8; ++j) {
                float4 x0 = *(const float4*)(X + j * 8);
                float4 x1 = *(const float4*)(X + j * 8 + 4);
                uint4 v;
                v.x = pkrtz(x0.x, x0.y); v.y = pkrtz(x0.z, x0.w);
                v.z = pkrtz(x1.x, x1.y); v.w = pkrtz(x1.z, x1.w);
                *(uint4*)((char*)Xl + ((r * 1024 + s * FPT * 2 + j * 16) ^ swz)) = v;
            }
        }
    }
    __syncthreads();

    f32x16 acc[NT];
    #pragma unroll
    for (int nt = 0; nt < NT; ++nt)
        #pragma unroll
        for (int i = 0; i < 16; ++i) acc[nt][i] = 0.f;

    const f16* wp[NT];
    #pragma unroll
    for (int nt = 0; nt < NT; ++nt)
        wp[nt] = Wpk_m + ((size_t)((colw / 32 + nt) * 64 + half_)) * 256 + lq * 8;

    const unsigned aswz = (lq & 7) << 4;

    #pragma unroll 4
    for (int ks = 0; ks < 32; ++ks) {
        f16x8 a = *(const f16x8*)((char*)Xl + ((lq * 1024 + ks * 32 + half_ * 16) ^ aswz));
        f16x8 bfr[NT];
        #pragma unroll
        for (int nt = 0; nt < NT; ++nt)
            bfr[nt] = *(const f16x8*)(wp[nt] + (size_t)ks * 512);
        #pragma unroll
        for (int nt = 0; nt < NT; ++nt) {
            if (OUTMODE == 2)
                acc[nt] = __builtin_amdgcn_mfma_f32_32x32x16_f16(bfr[nt], a, acc[nt], 0, 0, 0);
            else
                acc[nt] = __builtin_amdgcn_mfma_f32_32x32x16_f16(a, bfr[nt], acc[nt], 0, 0, 0);
        }
    }

    if (OUTMODE == 2) {
        const int b  = row0 >> 9;
        const int cb = (row0 >> 5) & 15;
        f16* Kp = (f16*)Yv + (size_t)(b * H_ + w) * 32768;
        #pragma unroll
        for (int nt = 0; nt < NT; ++nt)
            #pragma unroll
            for (int g = 0; g < 4; ++g) {
                const int n0 = w * 64 + nt * 32 + 8 * g + 4 * half_;
                const float4 b4 = *(const float4*)&bias[n0];
                const int ks2 = nt * 2 + (g >> 1);
                uint2 v;
                v.x = pkrtz(acc[nt][4 * g + 0] + b4.x, acc[nt][4 * g + 1] + b4.y);
                v.y = pkrtz(acc[nt][4 * g + 2] + b4.z, acc[nt][4 * g + 3] + b4.w);
                *(uint2*)&Kp[(cb * 4 + ks2) * 512 + (g & 1) * 256 + lq * 8 + half_ * 4] = v;
            }
    } else if (OUTMODE == 1) {
        const int b  = row0 >> 9;
        const int cB = row0 & 511;
        const int tt = cB >> 6;
        const int kbase = (cB >> 4) & 3;
        f16* Vp = (f16*)Yv + (size_t)(b * H_ + w) * 32768;
        #pragma unroll
        for (int nt = 0; nt < NT; ++nt) {
            const float bv = bias[w * 64 + nt * 32 + lq];
            #pragma unroll
            for (int g = 0; g < 4; ++g) {
                const int ks2 = kbase + (g >> 1);
                uint2 v;
                v.x = pkrtz(acc[nt][4 * g + 0] + bv, acc[nt][4 * g + 1] + bv);
                v.y = pkrtz(acc[nt][4 * g + 2] + bv, acc[nt][4 * g + 3] + bv);
                *(uint2*)&Vp[((tt * 4 + ks2) * 2 + nt) * 512 + (g & 1) * 256 + lq * 8 + half_ * 4] = v;
            }
        }
    } else {
        #pragma unroll
        for (int nt = 0; nt < NT; ++nt) {
            const float bv = bias[colw + nt * 32 + lq];
            #pragma unroll
            for (int r = 0; r < 16; ++r) {
                const int row = row0 + (r & 3) + 8 * (r >> 2) + 4 * half_;
                const float v = acc[nt][r] + bv;
                const size_t off = (size_t)row * 512 + colw + nt * 32 + lq;
                if (OUTF32) ((float*)Yv)[off] = v;
                else        ((f16*)Yv)[off]   = (f16)v;
            }
        }
    }
}

__global__ __launch_bounds__(512) void gemm_qkv(
    const float* __restrict__ query, const float* __restrict__ key,
    const float* __restrict__ value, const f16* __restrict__ Wpk,
    const float* __restrict__ bq, const float* __restrict__ bk,
    const float* __restrict__ bv,
    void* __restrict__ Qb, void* __restrict__ Kpk, void* __restrict__ Vpk)
{
    __shared__ f16 Xl[32 * 512];
    const int wg  = blockIdx.x;
    const int xcd = wg & 7;
    const int i   = wg >> 3;
    const int pg  = xcd * 96 + i;
    const int z   = pg >> 8;
    const int y   = pg & 255;
    const int row0 = y * 32;

    if (z == 0)
        gemm_stream_core<0, 0, 0, 8, 2>(query, Wpk,          bq, Qb,  row0, 0, Xl);
    else if (z == 1)
        gemm_stream_core<0, 0, 2, 8, 2>(key,   Wpk + 262144, bk, Kpk, row0, 0, Xl);
    else
        gemm_stream_core<0, 0, 1, 8, 2>(value, Wpk + 524288, bv, Vpk, row0, 0, Xl);
}

__global__ __launch_bounds__(256) void gemm_o(
    const void* __restrict__ X, const f16* __restrict__ Wpk,
    const float* __restrict__ bo, void* __restrict__ Y)
{
    __shared__ f16 Xl[32 * 512];
    const int wg  = blockIdx.x;
    const int xcd = wg & 7;
    const int i   = wg >> 3;
    const int pg  = xcd * 64 + i;
    const int cb  = pg & 1;
    const int y   = pg >> 1;
    gemm_stream_core<1, 1, 0, 4, 2>(X, Wpk + 786432, bo, Y, y * 32, cb * 256, Xl);
}

// ---------------------------------------------------------------------------
// Flash attention: 4 independent waves / 256-thr block (R18/R20-proven best).
// No register clamp; V-fragment loads after QK MFMAs (live-range split).
// ---------------------------------------------------------------------------
__global__ __launch_bounds__(256) void attn_kernel(
    const f16* __restrict__ Q, const f16* __restrict__ Kpk,
    const f16* __restrict__ Vpk, const float* __restrict__ Wg,
    const float* __restrict__ bg, const float* __restrict__ lam1,
    f16* __restrict__ ATT)
{
    const int tid  = threadIdx.x;
    const int w    = tid >> 6;        // independent wave id
    const int lane = tid & 63;
    const int lq   = lane & 31;
    const int half = lane >> 5;
    const int bh   = blockIdx.x;      // same bh -> same XCD
    const int b    = bh >> 3;
    const int h    = bh & 7;
    const int q0w  = blockIdx.y * 128 + w * 32;
    const int q    = q0w + lq;

    const float sg  = 1.f / (1.f + __expf(-lam1[0]));
    const float osg = 1.f - sg;

    // Q fragments (B-operand)
    f16x8 qh[4];
    {
        const f16* qrow = Q + ((size_t)(b * L_ + q) * DM_ + h * DK_);
        #pragma unroll
        for (int db = 0; db < 4; ++db)
            qh[db] = *(const f16x8*)&qrow[db * 16 + 8 * half];
    }

    // fused gamma: g = q_row . Wg^T + bg ; qp = (|g|+1)^-2
    float A0, A1, qpw;
    {
        float g0 = 0.f, g1 = 0.f;
        #pragma unroll
        for (int db = 0; db < 4; ++db)
            #pragma unroll
            for (int j = 0; j < 8; ++j) {
                const int d = db * 16 + 8 * half + j;
                const float qv = (float)qh[db][j];
                g0 = fmaf(qv, Wg[d], g0);
                g1 = fmaf(qv, Wg[64 + d], g1);
            }
        g0 += __shfl_xor(g0, 32);
        g1 += __shfl_xor(g1, 32);
        g0 += bg[0];
        g1 += bg[1];
        const float t0 = fabsf(g0) + 1.f, t1 = fabsf(g1) + 1.f;
        const float p0 = 1.f / (t0 * t0), p1 = 1.f / (t1 * t1);
        A0 = -NLOG2E_H_ * p0;       // c >= q (triu)
        A1 = -NLOG2E_H_ * p1;       // c <  q (tril)
        float mn = NLOG2E_H_ * fminf(p0, p1);
        #pragma unroll
        for (int off = 1; off < 64; off <<= 1) mn = fminf(mn, __shfl_xor(mn, off));
        qpw = mn;
    }

    f32x16 aS0, aS1, aA0, aA1;
    #pragma unroll
    for (int i = 0; i < 16; ++i) { aS0[i] = 0.f; aS1[i] = 0.f; aA0[i] = 0.f; aA1[i] = 0.f; }
    float m2 = -3.0e38f, sumS = 0.f, sumA = 0.f;

    const f16* Kp = Kpk + (size_t)(b * H_ + h) * 32768;
    const f16* Vp = Vpk + (size_t)(b * H_ + h) * 32768;
    const int  fo = half * 256 + lq * 8;

    for (int t = 0; t < 8; ++t) {
        const int c0 = t * 64;

        // K fragment loads (1KB contiguous per instr)
        f16x8 ka[4], kb2[4];
        #pragma unroll
        for (int db = 0; db < 4; ++db) {
            ka[db]  = *(const f16x8*)&Kp[(t * 2 * 4 + db) * 512 + fo];
            kb2[db] = *(const f16x8*)&Kp[((t * 2 + 1) * 4 + db) * 512 + fo];
        }

        // S^T = K . Q^T
        f32x16 s2a, s2b;
        #pragma unroll
        for (int i = 0; i < 16; ++i) { s2a[i] = 0.f; s2b[i] = 0.f; }
        __builtin_amdgcn_s_setprio(1);
        #pragma unroll
        for (int db = 0; db < 4; ++db) {
            s2a = __builtin_amdgcn_mfma_f32_32x32x16_f16(ka[db],  qh[db], s2a, 0, 0, 0);
            s2b = __builtin_amdgcn_mfma_f32_32x32x16_f16(kb2[db], qh[db], s2b, 0, 0, 0);
        }
        __builtin_amdgcn_s_setprio(0);

        // V fragment loads: latency hides under softmax VALU; K regs dead.
        f16x8 vfa[4], vfb[4];
        #pragma unroll
        for (int ks = 0; ks < 4; ++ks) {
            vfa[ks] = *(const f16x8*)&Vp[((t * 4 + ks) * 2 + 0) * 512 + fo];
            vfb[ks] = *(const f16x8*)&Vp[((t * 4 + ks) * 2 + 1) * 512 + fo];
        }

        // online max, exact skip (rescale only when the max actually moves)
        float tm = s2a[0];
        #pragma unroll
        for (int i = 1; i < 16; ++i) tm = fmaxf(tm, s2a[i]);
        #pragma unroll
        for (int i = 0; i < 16; ++i) tm = fmaxf(tm, s2b[i]);
        tm = fmaxf(tm, __shfl_xor(tm, 32));
        if (__any(tm > m2)) {
            const float nm = fmaxf(m2, tm);
            const float sc = exp2f((m2 - nm) * LOG2E_);
            m2 = nm;
            sumS *= sc;
            #pragma unroll
            for (int r = 0; r < 16; ++r) {
                const float s_ = __shfl(sc, (r & 3) + 8 * (r >> 2) + 4 * half);
                aS0[r] *= s_;
                aS1[r] *= s_;
            }
        }

        // P: exp, pack, permlane-swap into A-fragments, PV MFMAs
        const float nmL = m2 * LOG2E_;
        #pragma unroll
        for (int sub = 0; sub < 2; ++sub) {
            const f32x16& s2 = sub ? s2b : s2a;
            #pragma unroll
            for (int ksl = 0; ksl < 2; ++ksl) {
                const int rb = ksl * 8;
                float p[8];
                #pragma unroll
                for (int rr = 0; rr < 8; ++rr) {
                    p[rr] = exp2f(fmaf(s2[rb + rr], LOG2E_, -nmL));
                    sumS += p[rr];
                }
                union { unsigned u[4]; f16x8 v; } f;
                f.u[0] = pkrtz(p[0], p[1]);
                f.u[1] = pkrtz(p[2], p[3]);
                f.u[2] = pkrtz(p[4], p[5]);
                f.u[3] = pkrtz(p[6], p[7]);
                plswap(f.u[0], f.u[2]);
                plswap(f.u[1], f.u[3]);
                const int ks = sub * 2 + ksl;
                __builtin_amdgcn_s_setprio(1);
                aS0 = __builtin_amdgcn_mfma_f32_32x32x16_f16(f.v, vfa[ks], aS0, 0, 0, 0);
                aS1 = __builtin_amdgcn_mfma_f32_32x32x16_f16(f.v, vfb[ks], aS1, 0, 0, 0);
                __builtin_amdgcn_s_setprio(0);
            }
        }

        // adjacency branch (band-skip far tiles; diagonal tile never skipped)
        int gl_ = q0w - (c0 + 63);
        int gh_ = c0 - (q0w + 31);
        int dmin = gl_ > gh_ ? gl_ : gh_;
        if (dmin < 0) dmin = 0;
        if (qpw * (float)(dmin * dmin) < 40.0f) {
            #pragma unroll
            for (int sub = 0; sub < 2; ++sub) {
                #pragma unroll
                for (int ksl = 0; ksl < 2; ++ksl) {
                    float a[8];
                    #pragma unroll
                    for (int rr = 0; rr < 8; ++rr) {
                        const int kk = (rr & 3) + 8 * (rr >> 2) + 16 * ksl + 4 * half;
                        const int diff = q - (c0 + sub * 32 + kk);
                        const float fd = (float)diff;
                        const float coef = diff > 0 ? A1 : A0;
                        a[rr] = exp2f(coef * fd * fd);
                        sumA += a[rr];
                    }
                    union { unsigned u[4]; f16x8 v; } f;
                    f.u[0] = pkrtz(a[0], a[1]);
                    f.u[1] = pkrtz(a[2], a[3]);
                    f.u[2] = pkrtz(a[4], a[5]);
                    f.u[3] = pkrtz(a[6], a[7]);
                    plswap(f.u[0], f.u[2]);
                    plswap(f.u[1], f.u[3]);
                    const int ks = sub * 2 + ksl;
                    __builtin_amdgcn_s_setprio(1);
                    aA0 = __builtin_amdgcn_mfma_f32_32x32x16_f16(f.v, vfa[ks], aA0, 0, 0, 0);
                    aA1 = __builtin_amdgcn_mfma_f32_32x32x16_f16(f.v, vfb[ks], aA1, 0, 0, 0);
                    __builtin_amdgcn_s_setprio(0);
                }
            }
        }
    }

    // epilogue: mix branches, degree-normalize, store
    const float St = sumS + __shfl_xor(sumS, 32);
    const float At = sumA + __shfl_xor(sumA, 32);
    const float den = sg * St + osg * At + 1e-9f;
    #pragma unroll
    for (int r = 0; r < 16; ++r) {
        const int row = (r & 3) + 8 * (r >> 2) + 4 * half;
        const float dn = __shfl(den, row);
        const float o0 = (sg * aS0[r] + osg * aA0[r]) / dn;
        const float o1 = (sg * aS1[r] + osg * aA1[r]) / dn;
        const size_t base = (size_t)(b * L_ + q0w + row) * DM_ + h * DK_;
        ATT[base + lq]      = (f16)o0;
        ATT[base + 32 + lq] = (f16)o1;
    }
}

// ---------------------------------------------------------------------------
extern "C" void kernel_launch(void* const* d_in, const int* in_sizes, int n_in,
                              void* d_out, int out_size, void* d_ws, size_t ws_size,
                              hipStream_t stream)
{
    (void)in_sizes; (void)n_in; (void)out_size; (void)ws_size;
    const float* query = (const float*)d_in[0];
    const float* key   = (const float*)d_in[1];
    const float* value = (const float*)d_in[2];
    const float* Wq = (const float*)d_in[3];  const float* bq = (const float*)d_in[4];
    const float* Wk = (const float*)d_in[5];  const float* bk = (const float*)d_in[6];
    const float* Wv = (const float*)d_in[7];  const float* bv = (const float*)d_in[8];
    const float* Wg = (const float*)d_in[9];  const float* bg = (const float*)d_in[10];
    const float* lam1 = (const float*)d_in[11];
    const float* Wo = (const float*)d_in[12]; const float* bo = (const float*)d_in[13];

    f16* ws16 = (f16*)d_ws;
    const size_t NR = (size_t)B_ * L_ * DM_;
    f16* Kpkb = ws16;
    f16* Vpkb = ws16 + NR;
    f16* Qb   = ws16 + 2 * NR;
    f16* Wpkb = ws16 + 3 * NR;
    f16* ATTb = Qb;   // safe alias: each wave reads exactly the Q cells it later writes

    convw_pack<<<512, 256, 0, stream>>>(Wq, Wk, Wv, Wo, Wpkb);

    gemm_qkv<<<768, 512, 0, stream>>>(query, key, value, Wpkb, bq, bk, bv,
                                      Qb, Kpkb, Vpkb);

    dim3 ga(H_ * B_, L_ / 128);   // (128, 4) x 256 thr = 4 independent waves/block
    attn_kernel<<<ga, 256, 0, stream>>>(Qb, Kpkb, Vpkb, Wg, bg, lam1, ATTb);

    gemm_o<<<512, 256, 0, stream>>>(Qb, Wpkb, bo, (float*)d_out);
}